// Round 9
// baseline (113.876 us; speedup 1.0000x reference)
//
#include <hip/hip_runtime.h>
#include <math.h>

// Problem constants: s_len=t_len=4, B=8, C=64, T=256, D=16, H=512, F=32
typedef _Float16 half_t;
typedef _Float16 h2 __attribute__((ext_vector_type(2)));
typedef _Float16 h4 __attribute__((ext_vector_type(4)));
typedef _Float16 h8 __attribute__((ext_vector_type(8)));
typedef float f4 __attribute__((ext_vector_type(4)));
static constexpr float REPS = 1e-6f;

// ---------------------------------------------------------------------------
// k_prep2 = wconv (blocks 0-512) + x2h (blocks 513-768).
// ---------------------------------------------------------------------------
__global__ __launch_bounds__(256) void k_prep2(const float* __restrict__ tkw1, const float* __restrict__ tqw1,
                                               const float* __restrict__ tkw2, const float* __restrict__ tqw2,
                                               const float* __restrict__ tkb1, const float* __restrict__ tqb1,
                                               const float* __restrict__ tkb2, const float* __restrict__ tqb2,
                                               half_t* __restrict__ W1t, half_t* __restrict__ W2t,
                                               float* __restrict__ Bc1, float* __restrict__ Bc2,
                                               float* __restrict__ part,
                                               const float* __restrict__ fs, const float* __restrict__ ft,
                                               half_t* __restrict__ Xh, float* __restrict__ nrm) {
  __shared__ float T[64][65];
  int bid = blockIdx.x;
  int tid = threadIdx.x;
  if (bid < 256) {  // W1: [l][256 k][512 n] -> [z][512 n][256 k]
    int z = bid >> 5, tile = bid & 31;
    int kt = tile >> 3, ntile = tile & 7;
    const float* src = (z < 4 ? tkw1 : tqw1) + (size_t)(z & 3) * 256 * 512;
#pragma unroll
    for (int q = 0; q < 16; q++) {
      int e = q * 256 + tid;
      int r = e >> 6, c = e & 63;
      T[r][c] = src[(size_t)(kt * 64 + r) * 512 + ntile * 64 + c];
    }
    __syncthreads();
#pragma unroll
    for (int q = 0; q < 16; q++) {
      int e = q * 256 + tid;
      int nn = e >> 6, kk = e & 63;
      W1t[(size_t)z * 512 * 256 + (size_t)(ntile * 64 + nn) * 256 + kt * 64 + kk] = (half_t)T[kk][nn];
    }
  } else if (bid < 512) {  // W2: [l][512 k][256 n] -> [z][256 n][512 k]
    int bb = bid - 256;
    int z = bb >> 5, tile = bb & 31;
    int kt = tile >> 2, ntile = tile & 3;
    const float* src = (z < 4 ? tkw2 : tqw2) + (size_t)(z & 3) * 512 * 256;
#pragma unroll
    for (int q = 0; q < 16; q++) {
      int e = q * 256 + tid;
      int r = e >> 6, c = e & 63;
      T[r][c] = src[(size_t)(kt * 64 + r) * 256 + ntile * 64 + c];
    }
    __syncthreads();
#pragma unroll
    for (int q = 0; q < 16; q++) {
      int e = q * 256 + tid;
      int nn = e >> 6, kk = e & 63;
      W2t[(size_t)z * 256 * 512 + (size_t)(ntile * 64 + nn) * 512 + kt * 64 + kk] = (half_t)T[kk][nn];
    }
  } else if (bid == 512) {
    for (int e = tid; e < 4096; e += 256) {
      int z = e >> 9, n = e & 511;
      Bc1[e] = (z < 4 ? tkb1 : tqb1)[(z & 3) * 512 + n];
    }
    for (int e = tid; e < 2048; e += 256) {
      int z = e >> 8, n = e & 255;
      Bc2[e] = (z < 4 ? tkb2 : tqb2)[(z & 3) * 256 + n];
    }
    for (int e = tid; e < 16384; e += 256) part[e] = 0.f;
  } else {  // x2h: bid2 = tensor*128 + l*32 + b*4 + tc
    int bid2 = bid - 513;
    int tensor = bid2 >> 7;
    int l = (bid2 >> 5) & 3;
    int b = (bid2 >> 2) & 7;
    int tc = bid2 & 3;
    int tl = tid >> 2;           // 0..63
    int d0 = (tid & 3) * 4;
    int t = tc * 64 + tl;
    const float* base = (tensor ? ft : fs) + (size_t)((l * 8 + b) * 64) * 4096 + t * 16 + d0;
    size_t row = (size_t)(tensor * 32 + l * 8 + b) * 256 + t;
    half_t* xrow = Xh + row * 1024 + d0;
    float acc = 0.f;
#pragma unroll 8
    for (int c = 0; c < 64; c++) {
      float4 v = *(const float4*)(base + (size_t)c * 4096);
      acc += v.x * v.x + v.y * v.y + v.z * v.z + v.w * v.w;
      h4 hv;
      hv[0] = (half_t)v.x; hv[1] = (half_t)v.y; hv[2] = (half_t)v.z; hv[3] = (half_t)v.w;
      *(h4*)(xrow + c * 16) = hv;
    }
    acc += __shfl_xor(acc, 1);
    acc += __shfl_xor(acc, 2);
    if ((tid & 3) == 0) nrm[row] = sqrtf(acc);
  }
}

// ---------------------------------------------------------------------------
// k_gs = gram_cos (blocks 0-255) + simg (blocks 256-767). 512 threads.
// gram_cos epilogue v2: scatter S to LDS tile -> linear coalesced float4 writes.
// ---------------------------------------------------------------------------
__global__ __launch_bounds__(512) void k_gs(const half_t* __restrict__ Xh,
                                            const float* __restrict__ nrm,
                                            half_t* __restrict__ simh,
                                            float* __restrict__ out_stu,
                                            float* __restrict__ out_tea,
                                            float* __restrict__ simg) {
  __shared__ __align__(16) char smem[35584];
  int bid = blockIdx.x;
  int tid = threadIdx.x;
  if (bid < 256) {
    // ---- gram_cos: BM=64 x BN=256, BK=64, 8 waves, wave tile 32x64 ----
    half_t* Bsm = (half_t*)smem;                       // 256*64 halves = 32 KB
    float* Tile = (float*)smem;                        // [32][260] fp32 (reuses Bsm)
    float* rspart = (float*)(smem + 33280);            // [64][4]
    float* rowsumS = (float*)(smem + 34304);           // [64] (stores INVERSE rowsum)
    float* invn = (float*)(smem + 34560);              // [256]
    int mt = bid & 3;      // 0..3
    int z = bid >> 2;      // 0..63
    const half_t* Bb = Xh + (size_t)z * 256 * 1024;
    int w = tid >> 6, lane = tid & 63;
    int wm = w >> 2, wn = w & 3;
    int lr = lane & 15, lg = lane >> 4;
    f4 acc[2][4] = {};
    int r0 = tid >> 3, seg0 = tid & 7;
    int sw0 = (seg0 ^ (r0 & 7)) * 8;
    for (int kc = 0; kc < 1024; kc += 64) {
      h8 bv[4];
#pragma unroll
      for (int it = 0; it < 4; it++)
        bv[it] = *(const h8*)(Bb + (size_t)(it * 64 + r0) * 1024 + kc + seg0 * 8);
      __syncthreads();
#pragma unroll
      for (int it = 0; it < 4; it++)
        *(h8*)(Bsm + (it * 64 + r0) * 64 + sw0) = bv[it];
      __syncthreads();
#pragma unroll
      for (int kk = 0; kk < 2; kk++) {
        int g = kk * 4 + lg;
        h8 af[2], bf[4];
#pragma unroll
        for (int mf = 0; mf < 2; mf++) {
          int rA = mt * 64 + wm * 32 + mf * 16 + lr;
          af[mf] = *(const h8*)(Bsm + rA * 64 + ((g ^ (rA & 7)) * 8));
        }
#pragma unroll
        for (int nf = 0; nf < 4; nf++) {
          int rB = wn * 64 + nf * 16 + lr;
          bf[nf] = *(const h8*)(Bsm + rB * 64 + ((g ^ (rB & 7)) * 8));
        }
#pragma unroll
        for (int mf = 0; mf < 2; mf++)
#pragma unroll
          for (int nf = 0; nf < 4; nf++)
            acc[mf][nf] = __builtin_amdgcn_mfma_f32_16x16x32_f16(af[mf], bf[nf], acc[mf][nf], 0, 0, 0);
      }
    }
    // ---- epilogue v2 ----
    int tensor = z >> 5, l = (z >> 3) & 3, b = z & 7;
    const float* nz = nrm + z * 256;
    if (tid < 256) invn[tid] = 1.f / (nz[tid] + REPS);
    __syncthreads();   // invn visible; all Bsm MFMA reads complete
    int cols[4];
#pragma unroll
    for (int nf = 0; nf < 4; nf++) cols[nf] = wn * 64 + nf * 16 + lr;
    float rowpart[2][4];
#pragma unroll
    for (int mf = 0; mf < 2; mf++)
#pragma unroll
      for (int rg = 0; rg < 4; rg++) {
        int rib = wm * 32 + mf * 16 + lg * 4 + rg;
        float invr = invn[mt * 64 + rib];
        float p = 0.f;
#pragma unroll
        for (int nf = 0; nf < 4; nf++)
          p += fmaf(acc[mf][nf][rg] * (invr * invn[cols[nf]]), 0.5f, 0.5f);
        rowpart[mf][rg] = p;
      }
#pragma unroll
    for (int mf = 0; mf < 2; mf++)
#pragma unroll
      for (int rg = 0; rg < 4; rg++) {
        float p = rowpart[mf][rg];
        p += __shfl_xor(p, 1); p += __shfl_xor(p, 2);
        p += __shfl_xor(p, 4); p += __shfl_xor(p, 8);
        rowpart[mf][rg] = p;
      }
    if (lr == 0) {
#pragma unroll
      for (int mf = 0; mf < 2; mf++)
#pragma unroll
        for (int rg = 0; rg < 4; rg++)
          rspart[(wm * 32 + mf * 16 + lg * 4 + rg) * 4 + wn] = rowpart[mf][rg];
    }
    __syncthreads();
    if (tid < 64)
      rowsumS[tid] = 1.f / (rspart[tid * 4] + rspart[tid * 4 + 1] +
                            rspart[tid * 4 + 2] + rspart[tid * 4 + 3]);
    __syncthreads();
    float* outp = tensor ? out_tea : out_stu;
    for (int ph = 0; ph < 2; ph++) {
      if (wm == ph) {   // scatter this wave-half's S into the fp32 tile
#pragma unroll
        for (int mf = 0; mf < 2; mf++)
#pragma unroll
          for (int nf = 0; nf < 4; nf++)
#pragma unroll
            for (int rg = 0; rg < 4; rg++)
              Tile[(mf * 16 + lg * 4 + rg) * 260 + cols[nf]] = acc[mf][nf][rg];
      }
      __syncthreads();
      // linear coalesced write: 2048 float4s over 32 rows x 256 cols
#pragma unroll
      for (int it2 = 0; it2 < 4; it2++) {
        int fid = it2 * 512 + tid;
        int row = fid >> 6;
        int col = (fid & 63) << 2;
        int rib = ph * 32 + row;
        int t = mt * 64 + rib;
        float4 S4 = *(const float4*)(Tile + row * 260 + col);
        float invnr = invn[t];
        float rinv = rowsumS[rib];
        float4 vv;
        vv.x = fmaf(S4.x * (invnr * invn[col + 0]), 0.5f, 0.5f) * rinv;
        vv.y = fmaf(S4.y * (invnr * invn[col + 1]), 0.5f, 0.5f) * rinv;
        vv.z = fmaf(S4.z * (invnr * invn[col + 2]), 0.5f, 0.5f) * rinv;
        vv.w = fmaf(S4.w * (invnr * invn[col + 3]), 0.5f, 0.5f) * rinv;
        h4 sh;
        sh[0] = (half_t)S4.x; sh[1] = (half_t)S4.y;
        sh[2] = (half_t)S4.z; sh[3] = (half_t)S4.w;
        *(h4*)(simh + (size_t)z * 65536 + (size_t)t * 256 + col) = sh;
        size_t inner = ((size_t)(b * 256 + t)) * 256 + col;
        if (tensor == 0) {
          size_t base = (size_t)l * 4 * 524288;
#pragma unroll
          for (int j = 0; j < 4; j++)
            *(float4*)(outp + base + (size_t)j * 524288 + inner) = vv;
        } else {
#pragma unroll
          for (int i2 = 0; i2 < 4; i2++)
            *(float4*)(outp + ((size_t)(i2 * 4 + l)) * 524288 + inner) = vv;
        }
      }
      if (ph == 0) __syncthreads();
    }
  } else {
    // ---- simg: freq gram, two K-half passes. 32 LDS rows x 520 halves. ----
    half_t* X = (half_t*)smem;
    int sb = bid - 256;       // 0..511
    int tensor = sb >> 8;
    int l = (sb >> 6) & 3;
    int tc = sb & 63;
    int t0 = tc * 4;
    float acc = 0.f;
    int tl_c = tid >> 6;      // compute indices (tid<256 only)
    int ab = tid & 63;
    int bb = ab >> 3, aa = ab & 7;
    for (int kh = 0; kh < 2; kh++) {
#pragma unroll
      for (int j = 0; j < 4; j++) {
        int i = j * 512 + tid;
        int r = i >> 6, col = i & 63;
        int b = r & 7, tl = r >> 3;
        const half_t* src = Xh + ((size_t)(tensor * 32 + l * 8 + b) * 256 + t0 + tl) * 1024
                               + kh * 512 + col * 8;
        *(h8*)(X + r * 520 + col * 8) = *(const h8*)src;
      }
      __syncthreads();
      if (tid < 256) {
        const half_t* xa = X + (tl_c * 8 + bb) * 520;
        const half_t* xb = X + (tl_c * 8 + aa) * 520;
#pragma unroll 8
        for (int k = 0; k < 512; k += 8) {
          h8 va = *(const h8*)(xa + k);
          h8 vb = *(const h8*)(xb + k);
#if __has_builtin(__builtin_amdgcn_fdot2)
#pragma unroll
          for (int i = 0; i < 4; i++) {
            h2 pa, pb;
            pa[0] = va[2 * i]; pa[1] = va[2 * i + 1];
            pb[0] = vb[2 * i]; pb[1] = vb[2 * i + 1];
            acc = __builtin_amdgcn_fdot2(pa, pb, acc, false);
          }
#else
#pragma unroll
          for (int e = 0; e < 8; e++) acc += (float)va[e] * (float)vb[e];
#endif
        }
      }
      __syncthreads();
    }
    if (tid < 256)
      simg[(size_t)tensor * 65536 + ((size_t)(l * 8 + bb) * 256 + t0 + tl_c) * 8 + aa] = acc;
  }
}

// ---------------------------------------------------------------------------
// k_m1s = MLP GEMM1 (blocks 0-511) + cos_freq/fmlp (blocks 512-639). 256 thr.
// ---------------------------------------------------------------------------
__global__ __launch_bounds__(256) void k_m1s(const half_t* __restrict__ simh,
                                             const half_t* __restrict__ W1t,
                                             const float* __restrict__ Bc1,
                                             half_t* __restrict__ hbuf,
                                             const float* __restrict__ simg,
                                             const float* __restrict__ n,
                                             float* __restrict__ out_stu, float* __restrict__ out_tea,
                                             const float* __restrict__ qw1, const float* __restrict__ qb1,
                                             const float* __restrict__ qw2, const float* __restrict__ qb2,
                                             const float* __restrict__ kw1, const float* __restrict__ kb1,
                                             const float* __restrict__ kw2, const float* __restrict__ kb2,
                                             float* __restrict__ qout, float* __restrict__ kout) {
  __shared__ __align__(16) char smem[40352];
  int bid = blockIdx.x;
  int tid = threadIdx.x;
  if (bid < 512) {
    constexpr int K = 256, N = 512;
    half_t* Asm = (half_t*)smem;             // 128*64
    half_t* Bsm = (half_t*)(smem + 16384);   // 128*64
    int mt = bid & 15, nt = (bid >> 4) & 3, z = bid >> 6;
    int l = z & 3, path = z >> 2;
    const half_t* Ab = simh + ((size_t)((path == 0 ? 32 : 0) + l * 8)) * 256 * 256;
    const half_t* Bb = W1t + (size_t)z * 512 * 256;
    half_t* Ob = hbuf + (size_t)z * 2048 * 512;
    int wave = tid >> 6, lane = tid & 63;
    int wm = (wave >> 1) * 64, wn = (wave & 1) * 64;
    int lr = lane & 15, lg = lane >> 4;
    f4 acc[4][4] = {};
    int r0 = tid >> 3, seg0 = tid & 7;
    int sw0 = (seg0 ^ (r0 & 7)) * 8;
    for (int kc = 0; kc < K; kc += 64) {
      h8 av[4], bv[4];
#pragma unroll
      for (int j = 0; j < 4; j++) {
        av[j] = *(const h8*)(Ab + (size_t)(mt * 128 + r0 + 32 * j) * K + kc + seg0 * 8);
        bv[j] = *(const h8*)(Bb + (size_t)(nt * 128 + r0 + 32 * j) * K + kc + seg0 * 8);
      }
      __syncthreads();
#pragma unroll
      for (int j = 0; j < 4; j++) {
        *(h8*)(Asm + (r0 + 32 * j) * 64 + sw0) = av[j];
        *(h8*)(Bsm + (r0 + 32 * j) * 64 + sw0) = bv[j];
      }
      __syncthreads();
#pragma unroll
      for (int kk = 0; kk < 2; kk++) {
        h8 af[4], bf[4];
#pragma unroll
        for (int mf = 0; mf < 4; mf++) {
          int r = wm + mf * 16 + lr;
          af[mf] = *(const h8*)(Asm + r * 64 + (((kk * 4 + lg) ^ (r & 7)) * 8));
        }
#pragma unroll
        for (int nf = 0; nf < 4; nf++) {
          int r = wn + nf * 16 + lr;
          bf[nf] = *(const h8*)(Bsm + r * 64 + (((kk * 4 + lg) ^ (r & 7)) * 8));
        }
#pragma unroll
        for (int mf = 0; mf < 4; mf++)
#pragma unroll
          for (int nf = 0; nf < 4; nf++)
            acc[mf][nf] = __builtin_amdgcn_mfma_f32_16x16x32_f16(af[mf], bf[nf], acc[mf][nf], 0, 0, 0);
      }
    }
#pragma unroll
    for (int nf = 0; nf < 4; nf++) {
      int col = nt * 128 + wn + nf * 16 + lr;
      float bv2 = Bc1[z * N + col];
#pragma unroll
      for (int mf = 0; mf < 4; mf++) {
#pragma unroll
        for (int rg = 0; rg < 4; rg++) {
          int row = mt * 128 + wm + mf * 16 + lg * 4 + rg;
          float v = fmaxf(acc[mf][nf][rg] + bv2, 0.f);
          Ob[(size_t)row * N + col] = (half_t)v;
        }
      }
    }
  } else if (bid < 576) {
    // ---- cos_freq ----
    int bb = bid - 512;
    int tensor = bb >> 5;
    int lb = bb & 31;
    const float* sg = simg + (size_t)tensor * 65536;
    const float* nb2 = n + tensor * 8192;
    float* out = tensor ? out_tea : out_stu;
    int l = lb >> 3, b = lb & 7;
    int a = tid & 7;
    for (int tc = 0; tc < 8; tc++) {
      int t = tc * 32 + (tid >> 3);
      float nb = nb2[lb * 256 + t] + REPS;
      float na = nb2[(l * 8 + a) * 256 + t] + REPS;
      float v = (sg[((size_t)lb * 256 + t) * 8 + a] / (nb * na) + 1.f) * 0.5f;
      float w = v;
      for (int m = 1; m < 8; m <<= 1) w += __shfl_xor(w, m);
      v /= w;
      size_t inner = ((size_t)(b * 256 + t)) * 8 + a;
      if (tensor == 0) {
#pragma unroll
        for (int j = 0; j < 4; j++) out[((size_t)(l * 4 + j)) * 16384 + inner] = v;
      } else {
#pragma unroll
        for (int i = 0; i < 4; i++) out[((size_t)(i * 4 + l)) * 16384 + inner] = v;
      }
    }
  } else {
    // ---- freq MLP (tensor0 = student -> fq, tensor1 = teacher -> fk) ----
    float* sw1 = (float*)smem;                 // 256
    float* sb1 = (float*)(smem + 1024);        // 32
    float* sw2 = (float*)(smem + 1152);        // 1024
    float* sb2 = (float*)(smem + 5248);        // 32
    float* zs  = (float*)(smem + 5376);        // [256][33]
    float* pcn = (float*)(smem + 39168);       // [8][33]
    float* cn  = (float*)(smem + 40224);       // 32
    int bb = bid - 576;
    int tensor = bb >> 5;
    int lb = bb & 31;
    int l = lb >> 3;
    const float* w1 = tensor ? kw1 : qw1;
    const float* b1 = tensor ? kb1 : qb1;
    const float* w2 = tensor ? kw2 : qw2;
    const float* b2 = tensor ? kb2 : qb2;
    const float* sg = simg + (size_t)tensor * 65536;
    float* outp = tensor ? kout : qout;
    int t = tid;
    sw1[t] = w1[l * 256 + t];
    if (t < 32) { sb1[t] = b1[l * 32 + t]; sb2[t] = b2[l * 32 + t]; }
    for (int q = t; q < 1024; q += 256) sw2[q] = w2[l * 1024 + q];
    __syncthreads();
    float x[8];
#pragma unroll
    for (int a = 0; a < 8; a++) x[a] = sg[((size_t)lb * 256 + t) * 8 + a];
    float h[32];
#pragma unroll
    for (int f = 0; f < 32; f++) {
      float acc = sb1[f];
#pragma unroll
      for (int a = 0; a < 8; a++) acc += x[a] * sw1[a * 32 + f];
      h[f] = fmaxf(acc, 0.f);
    }
#pragma unroll
    for (int g = 0; g < 32; g++) {
      float acc = sb2[g];
#pragma unroll
      for (int f = 0; f < 32; f++) acc += h[f] * sw2[f * 32 + g];
      zs[t * 33 + g] = acc;
    }
    __syncthreads();
    {
      int col = t & 31, ch = t >> 5;
      float sq = 0.f;
      for (int r = ch * 32; r < ch * 32 + 32; r++) { float v = zs[r * 33 + col]; sq += v * v; }
      pcn[ch * 33 + col] = sq;
    }
    __syncthreads();
    if (t < 32) {
      float ssum = 0.f;
#pragma unroll
      for (int c = 0; c < 8; c++) ssum += pcn[c * 33 + t];
      cn[t] = sqrtf(ssum);
    }
    __syncthreads();
#pragma unroll
    for (int g = 0; g < 32; g++)
      outp[((size_t)lb * 256 + t) * 32 + g] = zs[t * 33 + g] / cn[g];
  }
}

// ---------------------------------------------------------------------------
// k_mfma2: Z = hbuf @ W2t^T + b2, 128x128 tile, K=512, N=256, + column-sumsq.
// ---------------------------------------------------------------------------
__global__ __launch_bounds__(256) void k_mfma2(const half_t* __restrict__ A,
                                               const half_t* __restrict__ Bt,
                                               const float* __restrict__ bias,
                                               half_t* __restrict__ out,
                                               float* __restrict__ part) {
  constexpr int K = 512, N = 256;
  __shared__ __align__(16) half_t Asm[128 * 64];
  __shared__ __align__(16) half_t Bsm[128 * 64];
  int z = blockIdx.z;
  const half_t* Ab = A + (size_t)z * 2048 * 512;
  const half_t* Bb = Bt + (size_t)z * 256 * 512;
  half_t* Ob = out + (size_t)z * 2048 * 256;
  int mt = blockIdx.x, nt = blockIdx.y;
  int tid = threadIdx.x;
  int wave = tid >> 6, lane = tid & 63;
  int wm = (wave >> 1) * 64, wn = (wave & 1) * 64;
  int lr = lane & 15, lg = lane >> 4;
  f4 acc[4][4] = {};
  int r0 = tid >> 3, seg0 = tid & 7;
  int sw0 = (seg0 ^ (r0 & 7)) * 8;
  for (int kc = 0; kc < K; kc += 64) {
    h8 av[4], bv[4];
#pragma unroll
    for (int j = 0; j < 4; j++) {
      av[j] = *(const h8*)(Ab + (size_t)(mt * 128 + r0 + 32 * j) * K + kc + seg0 * 8);
      bv[j] = *(const h8*)(Bb + (size_t)(nt * 128 + r0 + 32 * j) * K + kc + seg0 * 8);
    }
    __syncthreads();
#pragma unroll
    for (int j = 0; j < 4; j++) {
      *(h8*)(Asm + (r0 + 32 * j) * 64 + sw0) = av[j];
      *(h8*)(Bsm + (r0 + 32 * j) * 64 + sw0) = bv[j];
    }
    __syncthreads();
#pragma unroll
    for (int kk = 0; kk < 2; kk++) {
      h8 af[4], bf[4];
#pragma unroll
      for (int mf = 0; mf < 4; mf++) {
        int r = wm + mf * 16 + lr;
        af[mf] = *(const h8*)(Asm + r * 64 + (((kk * 4 + lg) ^ (r & 7)) * 8));
      }
#pragma unroll
      for (int nf = 0; nf < 4; nf++) {
        int r = wn + nf * 16 + lr;
        bf[nf] = *(const h8*)(Bsm + r * 64 + (((kk * 4 + lg) ^ (r & 7)) * 8));
      }
#pragma unroll
      for (int mf = 0; mf < 4; mf++)
#pragma unroll
        for (int nf = 0; nf < 4; nf++)
          acc[mf][nf] = __builtin_amdgcn_mfma_f32_16x16x32_f16(af[mf], bf[nf], acc[mf][nf], 0, 0, 0);
    }
  }
#pragma unroll
  for (int nf = 0; nf < 4; nf++) {
    int col = nt * 128 + wn + nf * 16 + lr;
    float bv2 = bias[z * N + col];
    float colsq = 0.f;
#pragma unroll
    for (int mf = 0; mf < 4; mf++) {
#pragma unroll
      for (int rg = 0; rg < 4; rg++) {
        int row = mt * 128 + wm + mf * 16 + lg * 4 + rg;
        float v = acc[mf][nf][rg] + bv2;
        Ob[(size_t)row * N + col] = (half_t)v;
        colsq += v * v;
      }
    }
    colsq += __shfl_xor(colsq, 16);
    colsq += __shfl_xor(colsq, 32);
    if (lg == 0) {
      int b = mt >> 1;
      atomicAdd(&part[((z * 8 + b) << 8) + col], colsq);
    }
  }
}

// ---------------------------------------------------------------------------
// k_att: blocks 0-127 = time att (block = (b, 16 t's), 256 thr, LDS invnorms);
//        blocks 128-383 = freq att (4 pairs per block).
// ---------------------------------------------------------------------------
__global__ __launch_bounds__(256) void k_att(const half_t* __restrict__ Zq,
                                             const half_t* __restrict__ Zk,
                                             const float* __restrict__ part,
                                             const float* __restrict__ fq,
                                             const float* __restrict__ fk,
                                             float* __restrict__ out_time,
                                             float* __restrict__ out_freq) {
  __shared__ float invq[4][256], invk[4][256];
  int bid = blockIdx.x;
  int tid = threadIdx.x;
  if (bid < 128) {
    int b = bid >> 4, tc = bid & 15;
    for (int e = tid; e < 1024; e += 256) {
      int i = e >> 8, s = e & 255;
      invq[i][s] = rsqrtf(part[(((4 + i) * 8 + b) << 8) + s]);
      invk[i][s] = rsqrtf(part[((i * 8 + b) << 8) + s]);
    }
    __syncthreads();
    int w = tid >> 6, lane = tid & 63;
    int s0 = lane * 4;
#pragma unroll
    for (int tt = 0; tt < 4; tt++) {
      int t = tc * 16 + w * 4 + tt;
      float qv[4][4], kv[4][4];
#pragma unroll
      for (int i = 0; i < 4; i++) {
        size_t lbO = (size_t)(i * 8 + b);
        h4 qh = *(const h4*)(Zq + (lbO * 256 + t) * 256 + s0);
        h4 kh = *(const h4*)(Zk + (lbO * 256 + t) * 256 + s0);
#pragma unroll
        for (int e = 0; e < 4; e++) {
          qv[i][e] = (float)qh[e] * invq[i][s0 + e];
          kv[i][e] = (float)kh[e] * invk[i][s0 + e];
        }
      }
      float acc[4][4];
#pragma unroll
      for (int i = 0; i < 4; i++)
#pragma unroll
        for (int j = 0; j < 4; j++) {
          float a = 0.f;
#pragma unroll
          for (int e = 0; e < 4; e++) a += qv[i][e] * kv[j][e];
          acc[i][j] = a;
        }
#pragma unroll
      for (int i = 0; i < 4; i++)
#pragma unroll
        for (int j = 0; j < 4; j++)
          for (int m = 32; m >= 1; m >>= 1) acc[i][j] += __shfl_xor(acc[i][j], m);
      if (lane < 16) {
        int i = lane >> 2, j = lane & 3;
        float mx = fmaxf(fmaxf(acc[i][0], acc[i][1]), fmaxf(acc[i][2], acc[i][3]));
        float sum = expf(acc[i][0] - mx) + expf(acc[i][1] - mx) + expf(acc[i][2] - mx) + expf(acc[i][3] - mx);
        out_time[((size_t)(b * 256 + t)) * 16 + lane] = expf(acc[i][j] - mx) / sum;
      }
    }
  } else {
    int sub = tid >> 6, lane = tid & 63;
    int pair = (bid - 128) * 4 + sub;     // 0..1023
    int b = pair >> 7, tp = pair & 127;
    int t = tp * 2 + (lane >> 5);
    int f = lane & 31;
    float qv[4], kv[4];
#pragma unroll
    for (int i = 0; i < 4; i++) {
      size_t lbO = (size_t)(i * 8 + b);
      qv[i] = fq[(lbO * 256 + t) * 32 + f];
      kv[i] = fk[(lbO * 256 + t) * 32 + f];
    }
    float acc[4][4];
#pragma unroll
    for (int i = 0; i < 4; i++)
#pragma unroll
      for (int j = 0; j < 4; j++) acc[i][j] = qv[i] * kv[j];
#pragma unroll
    for (int i = 0; i < 4; i++)
#pragma unroll
      for (int j = 0; j < 4; j++)
        for (int m = 16; m >= 1; m >>= 1) acc[i][j] += __shfl_xor(acc[i][j], m);
    int fl = lane & 31;
    if (fl < 16) {
      int i = fl >> 2, j = fl & 3;
      float mx = fmaxf(fmaxf(acc[i][0], acc[i][1]), fmaxf(acc[i][2], acc[i][3]));
      float sum = expf(acc[i][0] - mx) + expf(acc[i][1] - mx) + expf(acc[i][2] - mx) + expf(acc[i][3] - mx);
      out_freq[((size_t)(b * 256 + t)) * 16 + fl] = expf(acc[i][j] - mx) / sum;
    }
  }
}

// ---------------------------------------------------------------------------
extern "C" void kernel_launch(void* const* d_in, const int* in_sizes, int n_in,
                              void* d_out, int out_size, void* d_ws, size_t ws_size,
                              hipStream_t stream) {
  (void)in_sizes; (void)n_in; (void)out_size; (void)ws_size;
  const float* feat_s = (const float*)d_in[0];
  const float* feat_t = (const float*)d_in[1];
  const float* tk_w1 = (const float*)d_in[2];
  const float* tk_b1 = (const float*)d_in[3];
  const float* tk_w2 = (const float*)d_in[4];
  const float* tk_b2 = (const float*)d_in[5];
  const float* fk_w1 = (const float*)d_in[6];
  const float* fk_b1 = (const float*)d_in[7];
  const float* fk_w2 = (const float*)d_in[8];
  const float* fk_b2 = (const float*)d_in[9];
  const float* tq_w1 = (const float*)d_in[10];
  const float* tq_b1 = (const float*)d_in[11];
  const float* tq_w2 = (const float*)d_in[12];
  const float* tq_b2 = (const float*)d_in[13];
  const float* fq_w1 = (const float*)d_in[14];
  const float* fq_b1 = (const float*)d_in[15];
  const float* fq_w2 = (const float*)d_in[16];
  const float* fq_b2 = (const float*)d_in[17];

  float* ws = (float*)d_ws;
  // Xh16 region (33.5MB); after k_gs consumes it, h and Z alias it.
  half_t* Xh   = (half_t*)ws;                 // 16.8M halves
  half_t* hbuf = (half_t*)ws;                 // 8*2048*512 halves (alias, after gram)
  half_t* Zbuf = (half_t*)(ws + 4194304);     // 8*2048*256 halves (alias, after gram)
  half_t* simh = (half_t*)(ws + 8388608);     // 64*65536 halves
  half_t* W1t  = (half_t*)(ws + 10485760);    // 8*512*256 halves
  half_t* W2t  = (half_t*)(ws + 11010048);    // 8*256*512 halves
  float* Bc1   = ws + 11534336;               // 8*512
  float* Bc2   = ws + 11538432;               // 8*256
  float* simg  = ws + 11540480;               // 2*65536
  float* nrm   = ws + 11671552;               // 2*8192
  float* part  = ws + 11687936;               // 8*8*256 = 16384 (colnorm sumsq)
  float* fkb   = ws + 11704320;               // 262144
  float* fqb   = ws + 11966464;               // 262144

  float* out = (float*)d_out;
  float* out_stu_time = out;               // [4,4,8,256,256]
  float* out_stu_freq = out + 8388608;     // [4,4,8,256,8]
  float* out_tea_time = out + 8650752;     // [4,4,8,256,256]
  float* out_tea_freq = out + 17039360;    // [4,4,8,256,8]
  float* out_time_att = out + 17301504;    // [8,256,4,4]
  float* out_freq_att = out + 17334272;    // [8,256,4,4]

  // 1) weights + feat transpose/convert + norms + zero part (fused)
  hipLaunchKernelGGL(k_prep2, dim3(769), dim3(256), 0, stream,
                     tk_w1, tq_w1, tk_w2, tq_w2, tk_b1, tq_b1, tk_b2, tq_b2,
                     W1t, W2t, Bc1, Bc2, part, feat_s, feat_t, Xh, nrm);
  // 2) time gram + cosine outputs fused (coalesced epilogue), + freq gram
  hipLaunchKernelGGL(k_gs, dim3(768), dim3(512), 0, stream,
                     Xh, nrm, simh, out_stu_time, out_tea_time, simg);
  // 3) MLP GEMM1 alongside cos_freq + freq MLP (mixed blocks; h aliases Xh)
  hipLaunchKernelGGL(k_m1s, dim3(640), dim3(256), 0, stream,
                     simh, W1t, Bc1, hbuf, simg, nrm,
                     out_stu_freq, out_tea_freq,
                     fq_w1, fq_b1, fq_w2, fq_b2, fk_w1, fk_b1, fk_w2, fk_b2, fqb, fkb);
  // 4) MLP GEMM2 + fused column-sumsq atomics
  hipLaunchKernelGGL(k_mfma2, dim3(16, 2, 8), dim3(256), 0, stream,
                     hbuf, W2t, Bc2, Zbuf, part);
  // 5) attention (time: LDS invnorms + coalesced; freq: 4 pairs/block)
  hipLaunchKernelGGL(k_att, dim3(384), dim3(256), 0, stream,
                     Zbuf + (size_t)4 * 2048 * 256, Zbuf, part, fqb, fkb,
                     out_time_att, out_freq_att);
}

// Round 10
// 104.982 us; speedup vs baseline: 1.0847x; 1.0847x over previous
//
#include <hip/hip_runtime.h>
#include <math.h>

// Problem constants: s_len=t_len=4, B=8, C=64, T=256, D=16, H=512, F=32
typedef _Float16 half_t;
typedef _Float16 h2 __attribute__((ext_vector_type(2)));
typedef _Float16 h4 __attribute__((ext_vector_type(4)));
typedef _Float16 h8 __attribute__((ext_vector_type(8)));
typedef float f4 __attribute__((ext_vector_type(4)));
static constexpr float REPS = 1e-6f;

// ---------------------------------------------------------------------------
// k_prep2 = wconv (blocks 0-512) + x2h (blocks 513-768).
// ---------------------------------------------------------------------------
__global__ __launch_bounds__(256) void k_prep2(const float* __restrict__ tkw1, const float* __restrict__ tqw1,
                                               const float* __restrict__ tkw2, const float* __restrict__ tqw2,
                                               const float* __restrict__ tkb1, const float* __restrict__ tqb1,
                                               const float* __restrict__ tkb2, const float* __restrict__ tqb2,
                                               half_t* __restrict__ W1t, half_t* __restrict__ W2t,
                                               float* __restrict__ Bc1, float* __restrict__ Bc2,
                                               float* __restrict__ part,
                                               const float* __restrict__ fs, const float* __restrict__ ft,
                                               half_t* __restrict__ Xh, float* __restrict__ nrm) {
  __shared__ float T[64][65];
  int bid = blockIdx.x;
  int tid = threadIdx.x;
  if (bid < 256) {  // W1: [l][256 k][512 n] -> [z][512 n][256 k]
    int z = bid >> 5, tile = bid & 31;
    int kt = tile >> 3, ntile = tile & 7;
    const float* src = (z < 4 ? tkw1 : tqw1) + (size_t)(z & 3) * 256 * 512;
#pragma unroll
    for (int q = 0; q < 16; q++) {
      int e = q * 256 + tid;
      int r = e >> 6, c = e & 63;
      T[r][c] = src[(size_t)(kt * 64 + r) * 512 + ntile * 64 + c];
    }
    __syncthreads();
#pragma unroll
    for (int q = 0; q < 16; q++) {
      int e = q * 256 + tid;
      int nn = e >> 6, kk = e & 63;
      W1t[(size_t)z * 512 * 256 + (size_t)(ntile * 64 + nn) * 256 + kt * 64 + kk] = (half_t)T[kk][nn];
    }
  } else if (bid < 512) {  // W2: [l][512 k][256 n] -> [z][256 n][512 k]
    int bb = bid - 256;
    int z = bb >> 5, tile = bb & 31;
    int kt = tile >> 2, ntile = tile & 3;
    const float* src = (z < 4 ? tkw2 : tqw2) + (size_t)(z & 3) * 512 * 256;
#pragma unroll
    for (int q = 0; q < 16; q++) {
      int e = q * 256 + tid;
      int r = e >> 6, c = e & 63;
      T[r][c] = src[(size_t)(kt * 64 + r) * 256 + ntile * 64 + c];
    }
    __syncthreads();
#pragma unroll
    for (int q = 0; q < 16; q++) {
      int e = q * 256 + tid;
      int nn = e >> 6, kk = e & 63;
      W2t[(size_t)z * 256 * 512 + (size_t)(ntile * 64 + nn) * 512 + kt * 64 + kk] = (half_t)T[kk][nn];
    }
  } else if (bid == 512) {
    for (int e = tid; e < 4096; e += 256) {
      int z = e >> 9, n = e & 511;
      Bc1[e] = (z < 4 ? tkb1 : tqb1)[(z & 3) * 512 + n];
    }
    for (int e = tid; e < 2048; e += 256) {
      int z = e >> 8, n = e & 255;
      Bc2[e] = (z < 4 ? tkb2 : tqb2)[(z & 3) * 256 + n];
    }
    for (int e = tid; e < 16384; e += 256) part[e] = 0.f;
  } else {  // x2h: bid2 = tensor*128 + l*32 + b*4 + tc
    int bid2 = bid - 513;
    int tensor = bid2 >> 7;
    int l = (bid2 >> 5) & 3;
    int b = (bid2 >> 2) & 7;
    int tc = bid2 & 3;
    int tl = tid >> 2;           // 0..63
    int d0 = (tid & 3) * 4;
    int t = tc * 64 + tl;
    const float* base = (tensor ? ft : fs) + (size_t)((l * 8 + b) * 64) * 4096 + t * 16 + d0;
    size_t row = (size_t)(tensor * 32 + l * 8 + b) * 256 + t;
    half_t* xrow = Xh + row * 1024 + d0;
    float acc = 0.f;
#pragma unroll 8
    for (int c = 0; c < 64; c++) {
      float4 v = *(const float4*)(base + (size_t)c * 4096);
      acc += v.x * v.x + v.y * v.y + v.z * v.z + v.w * v.w;
      h4 hv;
      hv[0] = (half_t)v.x; hv[1] = (half_t)v.y; hv[2] = (half_t)v.z; hv[3] = (half_t)v.w;
      *(h4*)(xrow + c * 16) = hv;
    }
    acc += __shfl_xor(acc, 1);
    acc += __shfl_xor(acc, 2);
    if ((tid & 3) == 0) nrm[row] = sqrtf(acc);
  }
}

// ---------------------------------------------------------------------------
// k_gs = gram_cos (blocks 0-255, reg-prefetch k-loop) + simg (blocks 256-767,
// 512-thread k-split compute). 512 threads.
// ---------------------------------------------------------------------------
__global__ __launch_bounds__(512) void k_gs(const half_t* __restrict__ Xh,
                                            const float* __restrict__ nrm,
                                            half_t* __restrict__ simh,
                                            float* __restrict__ out_stu,
                                            float* __restrict__ out_tea,
                                            float* __restrict__ simg) {
  __shared__ __align__(16) char smem[35584];
  int bid = blockIdx.x;
  int tid = threadIdx.x;
  if (bid < 256) {
    // ---- gram_cos: BM=64 x BN=256, BK=64, 8 waves, wave tile 32x64 ----
    half_t* Bsm = (half_t*)smem;                       // 256*64 halves = 32 KB
    float* Tile = (float*)smem;                        // [32][260] fp32 (reuses Bsm)
    float* rspart = (float*)(smem + 33280);            // [64][4]
    float* rowsumS = (float*)(smem + 34304);           // [64] (INVERSE rowsum)
    float* invn = (float*)(smem + 34560);              // [256]
    int mt = bid & 3;      // 0..3
    int z = bid >> 2;      // 0..63
    const half_t* Bb = Xh + (size_t)z * 256 * 1024;
    int w = tid >> 6, lane = tid & 63;
    int wm = w >> 2, wn = w & 3;
    int lr = lane & 15, lg = lane >> 4;
    f4 acc[2][4] = {};
    int r0 = tid >> 3, seg0 = tid & 7;
    int sw0 = (seg0 ^ (r0 & 7)) * 8;
    h8 bv[4], bv2[4];
#pragma unroll
    for (int it = 0; it < 4; it++)
      bv[it] = *(const h8*)(Bb + (size_t)(it * 64 + r0) * 1024 + seg0 * 8);
    for (int kc = 0; kc < 1024; kc += 64) {
      __syncthreads();
#pragma unroll
      for (int it = 0; it < 4; it++)
        *(h8*)(Bsm + (it * 64 + r0) * 64 + sw0) = bv[it];
      __syncthreads();
      if (kc + 64 < 1024) {
#pragma unroll
        for (int it = 0; it < 4; it++)
          bv2[it] = *(const h8*)(Bb + (size_t)(it * 64 + r0) * 1024 + kc + 64 + seg0 * 8);
      }
#pragma unroll
      for (int kk = 0; kk < 2; kk++) {
        int g = kk * 4 + lg;
        h8 af[2], bf[4];
#pragma unroll
        for (int mf = 0; mf < 2; mf++) {
          int rA = mt * 64 + wm * 32 + mf * 16 + lr;
          af[mf] = *(const h8*)(Bsm + rA * 64 + ((g ^ (rA & 7)) * 8));
        }
#pragma unroll
        for (int nf = 0; nf < 4; nf++) {
          int rB = wn * 64 + nf * 16 + lr;
          bf[nf] = *(const h8*)(Bsm + rB * 64 + ((g ^ (rB & 7)) * 8));
        }
#pragma unroll
        for (int mf = 0; mf < 2; mf++)
#pragma unroll
          for (int nf = 0; nf < 4; nf++)
            acc[mf][nf] = __builtin_amdgcn_mfma_f32_16x16x32_f16(af[mf], bf[nf], acc[mf][nf], 0, 0, 0);
      }
      if (kc + 64 < 1024) {
#pragma unroll
        for (int it = 0; it < 4; it++) bv[it] = bv2[it];
      }
    }
    // ---- epilogue (coalesced v2) ----
    int tensor = z >> 5, l = (z >> 3) & 3, b = z & 7;
    const float* nz = nrm + z * 256;
    if (tid < 256) invn[tid] = 1.f / (nz[tid] + REPS);
    __syncthreads();
    int cols[4];
#pragma unroll
    for (int nf = 0; nf < 4; nf++) cols[nf] = wn * 64 + nf * 16 + lr;
    float rowpart[2][4];
#pragma unroll
    for (int mf = 0; mf < 2; mf++)
#pragma unroll
      for (int rg = 0; rg < 4; rg++) {
        int rib = wm * 32 + mf * 16 + lg * 4 + rg;
        float invr = invn[mt * 64 + rib];
        float p = 0.f;
#pragma unroll
        for (int nf = 0; nf < 4; nf++)
          p += fmaf(acc[mf][nf][rg] * (invr * invn[cols[nf]]), 0.5f, 0.5f);
        rowpart[mf][rg] = p;
      }
#pragma unroll
    for (int mf = 0; mf < 2; mf++)
#pragma unroll
      for (int rg = 0; rg < 4; rg++) {
        float p = rowpart[mf][rg];
        p += __shfl_xor(p, 1); p += __shfl_xor(p, 2);
        p += __shfl_xor(p, 4); p += __shfl_xor(p, 8);
        rowpart[mf][rg] = p;
      }
    if (lr == 0) {
#pragma unroll
      for (int mf = 0; mf < 2; mf++)
#pragma unroll
        for (int rg = 0; rg < 4; rg++)
          rspart[(wm * 32 + mf * 16 + lg * 4 + rg) * 4 + wn] = rowpart[mf][rg];
    }
    __syncthreads();
    if (tid < 64)
      rowsumS[tid] = 1.f / (rspart[tid * 4] + rspart[tid * 4 + 1] +
                            rspart[tid * 4 + 2] + rspart[tid * 4 + 3]);
    __syncthreads();
    float* outp = tensor ? out_tea : out_stu;
    for (int ph = 0; ph < 2; ph++) {
      if (wm == ph) {   // scatter this wave-half's S into the fp32 tile
#pragma unroll
        for (int mf = 0; mf < 2; mf++)
#pragma unroll
          for (int nf = 0; nf < 4; nf++)
#pragma unroll
            for (int rg = 0; rg < 4; rg++)
              Tile[(mf * 16 + lg * 4 + rg) * 260 + cols[nf]] = acc[mf][nf][rg];
      }
      __syncthreads();
      // linear coalesced write: 2048 float4s over 32 rows x 256 cols
#pragma unroll
      for (int it2 = 0; it2 < 4; it2++) {
        int fid = it2 * 512 + tid;
        int row = fid >> 6;
        int col = (fid & 63) << 2;
        int rib = ph * 32 + row;
        int t = mt * 64 + rib;
        float4 S4 = *(const float4*)(Tile + row * 260 + col);
        float invnr = invn[t];
        float rinv = rowsumS[rib];
        float4 vv;
        vv.x = fmaf(S4.x * (invnr * invn[col + 0]), 0.5f, 0.5f) * rinv;
        vv.y = fmaf(S4.y * (invnr * invn[col + 1]), 0.5f, 0.5f) * rinv;
        vv.z = fmaf(S4.z * (invnr * invn[col + 2]), 0.5f, 0.5f) * rinv;
        vv.w = fmaf(S4.w * (invnr * invn[col + 3]), 0.5f, 0.5f) * rinv;
        h4 sh;
        sh[0] = (half_t)S4.x; sh[1] = (half_t)S4.y;
        sh[2] = (half_t)S4.z; sh[3] = (half_t)S4.w;
        *(h4*)(simh + (size_t)z * 65536 + (size_t)t * 256 + col) = sh;
        size_t inner = ((size_t)(b * 256 + t)) * 256 + col;
        if (tensor == 0) {
          size_t base = (size_t)l * 4 * 524288;
#pragma unroll
          for (int j = 0; j < 4; j++)
            *(float4*)(outp + base + (size_t)j * 524288 + inner) = vv;
        } else {
#pragma unroll
          for (int i2 = 0; i2 < 4; i2++)
            *(float4*)(outp + ((size_t)(i2 * 4 + l)) * 524288 + inner) = vv;
        }
      }
      __syncthreads();
    }
  } else {
    // ---- simg: freq gram, two K-half passes, 512-thread k-split compute ----
    half_t* X = (half_t*)smem;                  // 32 x 520 halves = 33280 B
    float* red = (float*)(smem + 33280);        // 256 floats
    int sb = bid - 256;       // 0..511
    int tensor = sb >> 8;
    int l = (sb >> 6) & 3;
    int tc = sb & 63;
    int t0 = tc * 4;
    int kg = tid >> 8;        // 0/1: k-half within each staged pass
    int inner = tid & 255;
    int tl_c = inner >> 6;
    int ab = inner & 63;
    int bb = ab >> 3, aa = ab & 7;
    float acc = 0.f;
    for (int kh = 0; kh < 2; kh++) {
#pragma unroll
      for (int j = 0; j < 4; j++) {
        int i = j * 512 + tid;
        int r = i >> 6, col = i & 63;
        int b = r & 7, tl = r >> 3;
        const half_t* src = Xh + ((size_t)(tensor * 32 + l * 8 + b) * 256 + t0 + tl) * 1024
                               + kh * 512 + col * 8;
        *(h8*)(X + r * 520 + col * 8) = *(const h8*)src;
      }
      __syncthreads();
      {
        const half_t* xa = X + (tl_c * 8 + bb) * 520 + kg * 256;
        const half_t* xb = X + (tl_c * 8 + aa) * 520 + kg * 256;
#pragma unroll 8
        for (int k = 0; k < 256; k += 8) {
          h8 va = *(const h8*)(xa + k);
          h8 vb = *(const h8*)(xb + k);
#if __has_builtin(__builtin_amdgcn_fdot2)
#pragma unroll
          for (int i = 0; i < 4; i++) {
            h2 pa, pb;
            pa[0] = va[2 * i]; pa[1] = va[2 * i + 1];
            pb[0] = vb[2 * i]; pb[1] = vb[2 * i + 1];
            acc = __builtin_amdgcn_fdot2(pa, pb, acc, false);
          }
#else
#pragma unroll
          for (int e = 0; e < 8; e++) acc += (float)va[e] * (float)vb[e];
#endif
        }
      }
      __syncthreads();
    }
    if (kg == 1) red[inner] = acc;
    __syncthreads();
    if (kg == 0)
      simg[(size_t)tensor * 65536 + ((size_t)(l * 8 + bb) * 256 + t0 + tl_c) * 8 + aa] =
          acc + red[inner];
  }
}

// ---------------------------------------------------------------------------
// k_m1s = MLP GEMM1 (blocks 0-511, reg-prefetch) + cos_freq/fmlp (512-639).
// ---------------------------------------------------------------------------
__global__ __launch_bounds__(256) void k_m1s(const half_t* __restrict__ simh,
                                             const half_t* __restrict__ W1t,
                                             const float* __restrict__ Bc1,
                                             half_t* __restrict__ hbuf,
                                             const float* __restrict__ simg,
                                             const float* __restrict__ n,
                                             float* __restrict__ out_stu, float* __restrict__ out_tea,
                                             const float* __restrict__ qw1, const float* __restrict__ qb1,
                                             const float* __restrict__ qw2, const float* __restrict__ qb2,
                                             const float* __restrict__ kw1, const float* __restrict__ kb1,
                                             const float* __restrict__ kw2, const float* __restrict__ kb2,
                                             float* __restrict__ qout, float* __restrict__ kout) {
  __shared__ __align__(16) char smem[40352];
  int bid = blockIdx.x;
  int tid = threadIdx.x;
  if (bid < 512) {
    constexpr int K = 256, N = 512;
    half_t* Asm = (half_t*)smem;             // 128*64
    half_t* Bsm = (half_t*)(smem + 16384);   // 128*64
    int mt = bid & 15, nt = (bid >> 4) & 3, z = bid >> 6;
    int l = z & 3, path = z >> 2;
    const half_t* Ab = simh + ((size_t)((path == 0 ? 32 : 0) + l * 8)) * 256 * 256;
    const half_t* Bb = W1t + (size_t)z * 512 * 256;
    half_t* Ob = hbuf + (size_t)z * 2048 * 512;
    int wave = tid >> 6, lane = tid & 63;
    int wm = (wave >> 1) * 64, wn = (wave & 1) * 64;
    int lr = lane & 15, lg = lane >> 4;
    f4 acc[4][4] = {};
    int r0 = tid >> 3, seg0 = tid & 7;
    int sw0 = (seg0 ^ (r0 & 7)) * 8;
    h8 av[4], bv[4], av2[4], bv2[4];
#pragma unroll
    for (int j = 0; j < 4; j++) {
      av[j] = *(const h8*)(Ab + (size_t)(mt * 128 + r0 + 32 * j) * K + seg0 * 8);
      bv[j] = *(const h8*)(Bb + (size_t)(nt * 128 + r0 + 32 * j) * K + seg0 * 8);
    }
    for (int kc = 0; kc < K; kc += 64) {
      __syncthreads();
#pragma unroll
      for (int j = 0; j < 4; j++) {
        *(h8*)(Asm + (r0 + 32 * j) * 64 + sw0) = av[j];
        *(h8*)(Bsm + (r0 + 32 * j) * 64 + sw0) = bv[j];
      }
      __syncthreads();
      if (kc + 64 < K) {
#pragma unroll
        for (int j = 0; j < 4; j++) {
          av2[j] = *(const h8*)(Ab + (size_t)(mt * 128 + r0 + 32 * j) * K + kc + 64 + seg0 * 8);
          bv2[j] = *(const h8*)(Bb + (size_t)(nt * 128 + r0 + 32 * j) * K + kc + 64 + seg0 * 8);
        }
      }
#pragma unroll
      for (int kk = 0; kk < 2; kk++) {
        h8 af[4], bf[4];
#pragma unroll
        for (int mf = 0; mf < 4; mf++) {
          int r = wm + mf * 16 + lr;
          af[mf] = *(const h8*)(Asm + r * 64 + (((kk * 4 + lg) ^ (r & 7)) * 8));
        }
#pragma unroll
        for (int nf = 0; nf < 4; nf++) {
          int r = wn + nf * 16 + lr;
          bf[nf] = *(const h8*)(Bsm + r * 64 + (((kk * 4 + lg) ^ (r & 7)) * 8));
        }
#pragma unroll
        for (int mf = 0; mf < 4; mf++)
#pragma unroll
          for (int nf = 0; nf < 4; nf++)
            acc[mf][nf] = __builtin_amdgcn_mfma_f32_16x16x32_f16(af[mf], bf[nf], acc[mf][nf], 0, 0, 0);
      }
      if (kc + 64 < K) {
#pragma unroll
        for (int j = 0; j < 4; j++) { av[j] = av2[j]; bv[j] = bv2[j]; }
      }
    }
#pragma unroll
    for (int nf = 0; nf < 4; nf++) {
      int col = nt * 128 + wn + nf * 16 + lr;
      float bv3 = Bc1[z * N + col];
#pragma unroll
      for (int mf = 0; mf < 4; mf++) {
#pragma unroll
        for (int rg = 0; rg < 4; rg++) {
          int row = mt * 128 + wm + mf * 16 + lg * 4 + rg;
          float v = fmaxf(acc[mf][nf][rg] + bv3, 0.f);
          Ob[(size_t)row * N + col] = (half_t)v;
        }
      }
    }
  } else if (bid < 576) {
    // ---- cos_freq ----
    int bb = bid - 512;
    int tensor = bb >> 5;
    int lb = bb & 31;
    const float* sg = simg + (size_t)tensor * 65536;
    const float* nb2 = n + tensor * 8192;
    float* out = tensor ? out_tea : out_stu;
    int l = lb >> 3, b = lb & 7;
    int a = tid & 7;
    for (int tc = 0; tc < 8; tc++) {
      int t = tc * 32 + (tid >> 3);
      float nb = nb2[lb * 256 + t] + REPS;
      float na = nb2[(l * 8 + a) * 256 + t] + REPS;
      float v = (sg[((size_t)lb * 256 + t) * 8 + a] / (nb * na) + 1.f) * 0.5f;
      float w = v;
      for (int m = 1; m < 8; m <<= 1) w += __shfl_xor(w, m);
      v /= w;
      size_t inner = ((size_t)(b * 256 + t)) * 8 + a;
      if (tensor == 0) {
#pragma unroll
        for (int j = 0; j < 4; j++) out[((size_t)(l * 4 + j)) * 16384 + inner] = v;
      } else {
#pragma unroll
        for (int i = 0; i < 4; i++) out[((size_t)(i * 4 + l)) * 16384 + inner] = v;
      }
    }
  } else {
    // ---- freq MLP (tensor0 = student -> fq, tensor1 = teacher -> fk) ----
    float* sw1 = (float*)smem;                 // 256
    float* sb1 = (float*)(smem + 1024);        // 32
    float* sw2 = (float*)(smem + 1152);        // 1024
    float* sb2 = (float*)(smem + 5248);        // 32
    float* zs  = (float*)(smem + 5376);        // [256][33]
    float* pcn = (float*)(smem + 39168);       // [8][33]
    float* cn  = (float*)(smem + 40224);       // 32
    int bb = bid - 576;
    int tensor = bb >> 5;
    int lb = bb & 31;
    int l = lb >> 3;
    const float* w1 = tensor ? kw1 : qw1;
    const float* b1 = tensor ? kb1 : qb1;
    const float* w2 = tensor ? kw2 : qw2;
    const float* b2 = tensor ? kb2 : qb2;
    const float* sg = simg + (size_t)tensor * 65536;
    float* outp = tensor ? kout : qout;
    int t = tid;
    sw1[t] = w1[l * 256 + t];
    if (t < 32) { sb1[t] = b1[l * 32 + t]; sb2[t] = b2[l * 32 + t]; }
    for (int q = t; q < 1024; q += 256) sw2[q] = w2[l * 1024 + q];
    __syncthreads();
    float x[8];
#pragma unroll
    for (int a = 0; a < 8; a++) x[a] = sg[((size_t)lb * 256 + t) * 8 + a];
    float h[32];
#pragma unroll
    for (int f = 0; f < 32; f++) {
      float acc = sb1[f];
#pragma unroll
      for (int a = 0; a < 8; a++) acc += x[a] * sw1[a * 32 + f];
      h[f] = fmaxf(acc, 0.f);
    }
#pragma unroll
    for (int g = 0; g < 32; g++) {
      float acc = sb2[g];
#pragma unroll
      for (int f = 0; f < 32; f++) acc += h[f] * sw2[f * 32 + g];
      zs[t * 33 + g] = acc;
    }
    __syncthreads();
    {
      int col = t & 31, ch = t >> 5;
      float sq = 0.f;
      for (int r = ch * 32; r < ch * 32 + 32; r++) { float v = zs[r * 33 + col]; sq += v * v; }
      pcn[ch * 33 + col] = sq;
    }
    __syncthreads();
    if (t < 32) {
      float ssum = 0.f;
#pragma unroll
      for (int c = 0; c < 8; c++) ssum += pcn[c * 33 + t];
      cn[t] = sqrtf(ssum);
    }
    __syncthreads();
#pragma unroll
    for (int g = 0; g < 32; g++)
      outp[((size_t)lb * 256 + t) * 32 + g] = zs[t * 33 + g] / cn[g];
  }
}

// ---------------------------------------------------------------------------
// k_mfma2: Z = hbuf @ W2t^T + b2, 128x128 tile, K=512, reg-prefetch, colsumsq.
// ---------------------------------------------------------------------------
__global__ __launch_bounds__(256) void k_mfma2(const half_t* __restrict__ A,
                                               const half_t* __restrict__ Bt,
                                               const float* __restrict__ bias,
                                               half_t* __restrict__ out,
                                               float* __restrict__ part) {
  constexpr int K = 512, N = 256;
  __shared__ __align__(16) half_t Asm[128 * 64];
  __shared__ __align__(16) half_t Bsm[128 * 64];
  int z = blockIdx.z;
  const half_t* Ab = A + (size_t)z * 2048 * 512;
  const half_t* Bb = Bt + (size_t)z * 256 * 512;
  half_t* Ob = out + (size_t)z * 2048 * 256;
  int mt = blockIdx.x, nt = blockIdx.y;
  int tid = threadIdx.x;
  int wave = tid >> 6, lane = tid & 63;
  int wm = (wave >> 1) * 64, wn = (wave & 1) * 64;
  int lr = lane & 15, lg = lane >> 4;
  f4 acc[4][4] = {};
  int r0 = tid >> 3, seg0 = tid & 7;
  int sw0 = (seg0 ^ (r0 & 7)) * 8;
  h8 av[4], bv[4], av2[4], bv2[4];
#pragma unroll
  for (int j = 0; j < 4; j++) {
    av[j] = *(const h8*)(Ab + (size_t)(mt * 128 + r0 + 32 * j) * K + seg0 * 8);
    bv[j] = *(const h8*)(Bb + (size_t)(nt * 128 + r0 + 32 * j) * K + seg0 * 8);
  }
  for (int kc = 0; kc < K; kc += 64) {
    __syncthreads();
#pragma unroll
    for (int j = 0; j < 4; j++) {
      *(h8*)(Asm + (r0 + 32 * j) * 64 + sw0) = av[j];
      *(h8*)(Bsm + (r0 + 32 * j) * 64 + sw0) = bv[j];
    }
    __syncthreads();
    if (kc + 64 < K) {
#pragma unroll
      for (int j = 0; j < 4; j++) {
        av2[j] = *(const h8*)(Ab + (size_t)(mt * 128 + r0 + 32 * j) * K + kc + 64 + seg0 * 8);
        bv2[j] = *(const h8*)(Bb + (size_t)(nt * 128 + r0 + 32 * j) * K + kc + 64 + seg0 * 8);
      }
    }
#pragma unroll
    for (int kk = 0; kk < 2; kk++) {
      h8 af[4], bf[4];
#pragma unroll
      for (int mf = 0; mf < 4; mf++) {
        int r = wm + mf * 16 + lr;
        af[mf] = *(const h8*)(Asm + r * 64 + (((kk * 4 + lg) ^ (r & 7)) * 8));
      }
#pragma unroll
      for (int nf = 0; nf < 4; nf++) {
        int r = wn + nf * 16 + lr;
        bf[nf] = *(const h8*)(Bsm + r * 64 + (((kk * 4 + lg) ^ (r & 7)) * 8));
      }
#pragma unroll
      for (int mf = 0; mf < 4; mf++)
#pragma unroll
        for (int nf = 0; nf < 4; nf++)
          acc[mf][nf] = __builtin_amdgcn_mfma_f32_16x16x32_f16(af[mf], bf[nf], acc[mf][nf], 0, 0, 0);
    }
    if (kc + 64 < K) {
#pragma unroll
      for (int j = 0; j < 4; j++) { av[j] = av2[j]; bv[j] = bv2[j]; }
    }
  }
#pragma unroll
  for (int nf = 0; nf < 4; nf++) {
    int col = nt * 128 + wn + nf * 16 + lr;
    float bv3 = bias[z * N + col];
    float colsq = 0.f;
#pragma unroll
    for (int mf = 0; mf < 4; mf++) {
#pragma unroll
      for (int rg = 0; rg < 4; rg++) {
        int row = mt * 128 + wm + mf * 16 + lg * 4 + rg;
        float v = acc[mf][nf][rg] + bv3;
        Ob[(size_t)row * N + col] = (half_t)v;
        colsq += v * v;
      }
    }
    colsq += __shfl_xor(colsq, 16);
    colsq += __shfl_xor(colsq, 32);
    if (lg == 0) {
      int b = mt >> 1;
      atomicAdd(&part[((z * 8 + b) << 8) + col], colsq);
    }
  }
}

// ---------------------------------------------------------------------------
// k_att: blocks 0-127 = time att (block = (b, 16 t's), 256 thr, LDS invnorms);
//        blocks 128-383 = freq att (4 pairs per block).
// ---------------------------------------------------------------------------
__global__ __launch_bounds__(256) void k_att(const half_t* __restrict__ Zq,
                                             const half_t* __restrict__ Zk,
                                             const float* __restrict__ part,
                                             const float* __restrict__ fq,
                                             const float* __restrict__ fk,
                                             float* __restrict__ out_time,
                                             float* __restrict__ out_freq) {
  __shared__ float invq[4][256], invk[4][256];
  int bid = blockIdx.x;
  int tid = threadIdx.x;
  if (bid < 128) {
    int b = bid >> 4, tc = bid & 15;
    for (int e = tid; e < 1024; e += 256) {
      int i = e >> 8, s = e & 255;
      invq[i][s] = rsqrtf(part[(((4 + i) * 8 + b) << 8) + s]);
      invk[i][s] = rsqrtf(part[((i * 8 + b) << 8) + s]);
    }
    __syncthreads();
    int w = tid >> 6, lane = tid & 63;
    int s0 = lane * 4;
#pragma unroll
    for (int tt = 0; tt < 4; tt++) {
      int t = tc * 16 + w * 4 + tt;
      float qv[4][4], kv[4][4];
#pragma unroll
      for (int i = 0; i < 4; i++) {
        size_t lbO = (size_t)(i * 8 + b);
        h4 qh = *(const h4*)(Zq + (lbO * 256 + t) * 256 + s0);
        h4 kh = *(const h4*)(Zk + (lbO * 256 + t) * 256 + s0);
#pragma unroll
        for (int e = 0; e < 4; e++) {
          qv[i][e] = (float)qh[e] * invq[i][s0 + e];
          kv[i][e] = (float)kh[e] * invk[i][s0 + e];
        }
      }
      float acc[4][4];
#pragma unroll
      for (int i = 0; i < 4; i++)
#pragma unroll
        for (int j = 0; j < 4; j++) {
          float a = 0.f;
#pragma unroll
          for (int e = 0; e < 4; e++) a += qv[i][e] * kv[j][e];
          acc[i][j] = a;
        }
#pragma unroll
      for (int i = 0; i < 4; i++)
#pragma unroll
        for (int j = 0; j < 4; j++)
          for (int m = 32; m >= 1; m >>= 1) acc[i][j] += __shfl_xor(acc[i][j], m);
      if (lane < 16) {
        int i = lane >> 2, j = lane & 3;
        float mx = fmaxf(fmaxf(acc[i][0], acc[i][1]), fmaxf(acc[i][2], acc[i][3]));
        float sum = expf(acc[i][0] - mx) + expf(acc[i][1] - mx) + expf(acc[i][2] - mx) + expf(acc[i][3] - mx);
        out_time[((size_t)(b * 256 + t)) * 16 + lane] = expf(acc[i][j] - mx) / sum;
      }
    }
  } else {
    int sub = tid >> 6, lane = tid & 63;
    int pair = (bid - 128) * 4 + sub;     // 0..1023
    int b = pair >> 7, tp = pair & 127;
    int t = tp * 2 + (lane >> 5);
    int f = lane & 31;
    float qv[4], kv[4];
#pragma unroll
    for (int i = 0; i < 4; i++) {
      size_t lbO = (size_t)(i * 8 + b);
      qv[i] = fq[(lbO * 256 + t) * 32 + f];
      kv[i] = fk[(lbO * 256 + t) * 32 + f];
    }
    float acc[4][4];
#pragma unroll
    for (int i = 0; i < 4; i++)
#pragma unroll
      for (int j = 0; j < 4; j++) acc[i][j] = qv[i] * kv[j];
#pragma unroll
    for (int i = 0; i < 4; i++)
#pragma unroll
      for (int j = 0; j < 4; j++)
        for (int m = 16; m >= 1; m >>= 1) acc[i][j] += __shfl_xor(acc[i][j], m);
    int fl = lane & 31;
    if (fl < 16) {
      int i = fl >> 2, j = fl & 3;
      float mx = fmaxf(fmaxf(acc[i][0], acc[i][1]), fmaxf(acc[i][2], acc[i][3]));
      float sum = expf(acc[i][0] - mx) + expf(acc[i][1] - mx) + expf(acc[i][2] - mx) + expf(acc[i][3] - mx);
      out_freq[((size_t)(b * 256 + t)) * 16 + fl] = expf(acc[i][j] - mx) / sum;
    }
  }
}

// ---------------------------------------------------------------------------
extern "C" void kernel_launch(void* const* d_in, const int* in_sizes, int n_in,
                              void* d_out, int out_size, void* d_ws, size_t ws_size,
                              hipStream_t stream) {
  (void)in_sizes; (void)n_in; (void)out_size; (void)ws_size;
  const float* feat_s = (const float*)d_in[0];
  const float* feat_t = (const float*)d_in[1];
  const float* tk_w1 = (const float*)d_in[2];
  const float* tk_b1 = (const float*)d_in[3];
  const float* tk_w2 = (const float*)d_in[4];
  const float* tk_b2 = (const float*)d_in[5];
  const float* fk_w1 = (const float*)d_in[6];
  const float* fk_b1 = (const float*)d_in[7];
  const float* fk_w2 = (const float*)d_in[8];
  const float* fk_b2 = (const float*)d_in[9];
  const float* tq_w1 = (const float*)d_in[10];
  const float* tq_b1 = (const float*)d_in[11];
  const float* tq_w2 = (const float*)d_in[12];
  const float* tq_b2 = (const float*)d_in[13];
  const float* fq_w1 = (const float*)d_in[14];
  const float* fq_b1 = (const float*)d_in[15];
  const float* fq_w2 = (const float*)d_in[16];
  const float* fq_b2 = (const float*)d_in[17];

  float* ws = (float*)d_ws;
  // Xh16 region (33.5MB); after k_gs consumes it, h and Z alias it.
  half_t* Xh   = (half_t*)ws;                 // 16.8M halves
  half_t* hbuf = (half_t*)ws;                 // 8*2048*512 halves (alias, after gram)
  half_t* Zbuf = (half_t*)(ws + 4194304);     // 8*2048*256 halves (alias, after gram)
  half_t* simh = (half_t*)(ws + 8388608);     // 64*65536 halves
  half_t* W1t  = (half_t*)(ws + 10485760);    // 8*512*256 halves
  half_t* W2t  = (half_t*)(ws + 11010048);    // 8*256*512 halves
  float* Bc1   = ws + 11534336;               // 8*512
  float* Bc2   = ws + 11538432;               // 8*256
  float* simg  = ws + 11540480;               // 2*65536
  float* nrm   = ws + 11671552;               // 2*8192
  float* part  = ws + 11687936;               // 8*8*256 = 16384 (colnorm sumsq)
  float* fkb   = ws + 11704320;               // 262144
  float* fqb   = ws + 11966464;               // 262144

  float* out = (float*)d_out;
  float* out_stu_time = out;               // [4,4,8,256,256]
  float* out_stu_freq = out + 8388608;     // [4,4,8,256,8]
  float* out_tea_time = out + 8650752;     // [4,4,8,256,256]
  float* out_tea_freq = out + 17039360;    // [4,4,8,256,8]
  float* out_time_att = out + 17301504;    // [8,256,4,4]
  float* out_freq_att = out + 17334272;    // [8,256,4,4]

  // 1) weights + feat transpose/convert + norms + zero part (fused)
  hipLaunchKernelGGL(k_prep2, dim3(769), dim3(256), 0, stream,
                     tk_w1, tq_w1, tk_w2, tq_w2, tk_b1, tq_b1, tk_b2, tq_b2,
                     W1t, W2t, Bc1, Bc2, part, feat_s, feat_t, Xh, nrm);
  // 2) time gram + cosine outputs fused (prefetch k-loop), + freq gram
  hipLaunchKernelGGL(k_gs, dim3(768), dim3(512), 0, stream,
                     Xh, nrm, simh, out_stu_time, out_tea_time, simg);
  // 3) MLP GEMM1 (prefetch) alongside cos_freq + freq MLP
  hipLaunchKernelGGL(k_m1s, dim3(640), dim3(256), 0, stream,
                     simh, W1t, Bc1, hbuf, simg, nrm,
                     out_stu_freq, out_tea_freq,
                     fq_w1, fq_b1, fq_w2, fq_b2, fk_w1, fk_b1, fk_w2, fk_b2, fqb, fkb);
  // 4) MLP GEMM2 (prefetch) + fused column-sumsq atomics
  hipLaunchKernelGGL(k_mfma2, dim3(16, 2, 8), dim3(256), 0, stream,
                     hbuf, W2t, Bc2, Zbuf, part);
  // 5) attention (time: LDS invnorms + coalesced; freq: 4 pairs/block)
  hipLaunchKernelGGL(k_att, dim3(384), dim3(256), 0, stream,
                     Zbuf + (size_t)4 * 2048 * 256, Zbuf, part, fqb, fkb,
                     out_time_att, out_freq_att);
}